// Round 14
// baseline (1794.927 us; speedup 1.0000x reference)
//
#include <hip/hip_runtime.h>
#include <hip/hip_fp8.h>

#define N_ROWS 4096
#define H_DIM  1024
#define V_SIZE 32000

typedef int   i32x4 __attribute__((ext_vector_type(4)));
typedef int   i32x8 __attribute__((ext_vector_type(8)));
typedef float f32x4 __attribute__((ext_vector_type(4)));

typedef __attribute__((address_space(1))) void* gas_ptr;
typedef __attribute__((address_space(3))) void* las_ptr;

__global__ void zero_f32(float* __restrict__ p, int n) {
  int i = blockIdx.x * blockDim.x + threadIdx.x;
  if (i < n) p[i] = 0.0f;
}

__device__ __forceinline__ unsigned pk4_fp8(float a, float b, float c, float d) {
#if __has_builtin(__builtin_amdgcn_cvt_pk_fp8_f32)
  int v = __builtin_amdgcn_cvt_pk_fp8_f32(a, b, 0, false);
  v = __builtin_amdgcn_cvt_pk_fp8_f32(c, d, v, true);
  return (unsigned)v;
#else
  __hip_fp8_e4m3 qa(a), qb(b), qc(c), qd(d);
  return (unsigned)qa.__x | ((unsigned)qb.__x << 8) | ((unsigned)qc.__x << 16) |
         ((unsigned)qd.__x << 24);
#endif
}

// W path (Ws/Wt): fp32 -> fp8 e4m3 with the LDS swizzle PRE-BAKED (r9-verified):
// out[row*1024 + (k ^ ((row&7)<<4))] = fp8(in[row*1024 + k]).
__global__ void cvt_fp8(const float* __restrict__ in, unsigned char* __restrict__ out, int total16) {
  int idx = blockIdx.x * blockDim.x + threadIdx.x;
  int stride = gridDim.x * blockDim.x;
  for (; idx < total16; idx += stride) {
    unsigned row = (unsigned)idx >> 6;
    unsigned k0 = ((unsigned)idx & 63u) << 4;
    const float4* p = (const float4*)(in + (size_t)row * H_DIM + k0);
    float4 f0 = p[0], f1 = p[1], f2 = p[2], f3 = p[3];
    unsigned long long u0 = (unsigned long long)pk4_fp8(f0.x, f0.y, f0.z, f0.w) |
                            ((unsigned long long)pk4_fp8(f1.x, f1.y, f1.z, f1.w) << 32);
    unsigned long long u1 = (unsigned long long)pk4_fp8(f2.x, f2.y, f2.z, f2.w) |
                            ((unsigned long long)pk4_fp8(f3.x, f3.y, f3.z, f3.w) << 32);
    unsigned key = (row & 7u) << 4;
    unsigned char* ob = out + (size_t)row * H_DIM;
    *(unsigned long long*)(ob + (k0 ^ key)) = u0;
    *(unsigned long long*)(ob + ((k0 ^ key) + 8u)) = u1;
  }
}

// A path (x/tx): fp32 -> fp8 in FRAGMENT-LINEAR layout (r12/r13-verified): each
// MFMA A-fragment is one coalesced global_load_dwordx4 at base + lane*16.
__global__ void cvt_fragA(const float* __restrict__ in, unsigned char* __restrict__ out, int total16) {
  int idx = blockIdx.x * blockDim.x + threadIdx.x;
  int stride = gridDim.x * blockDim.x;
  for (; idx < total16; idx += stride) {
    unsigned row = (unsigned)idx >> 6;
    unsigned u16 = (unsigned)idx & 63u;
    const float4* p = (const float4*)(in + (size_t)row * H_DIM + u16 * 16u);
    float4 f0 = p[0], f1 = p[1], f2 = p[2], f3 = p[3];
    uint4 o;
    o.x = pk4_fp8(f0.x, f0.y, f0.z, f0.w);
    o.y = pk4_fp8(f1.x, f1.y, f1.z, f1.w);
    o.z = pk4_fp8(f2.x, f2.y, f2.z, f2.w);
    o.w = pk4_fp8(f3.x, f3.y, f3.z, f3.w);
    unsigned rg = row >> 4, c = row & 15u, kt = u16 >> 3, u = u16 & 7u;
    *(uint4*)(out + rg * 16384u + kt * 2048u + u * 256u + c * 16u) = o;
  }
}

__device__ __forceinline__ i32x8 cat8(i32x4 a, i32x4 b) {
  return __builtin_shufflevector(a, b, 0, 1, 2, 3, 4, 5, 6, 7);
}

// MX-scaled fp8 MFMA, unit scales (E8M0 127 = x1.0). Validated r8/r9.
__device__ __forceinline__ f32x4 mx_mfma(i32x8 a, i32x8 b, f32x4 c) {
  return __builtin_amdgcn_mfma_scale_f32_16x16x128_f8f6f4(
      a, b, c, 0 /*A=fp8*/, 0 /*B=fp8*/, 0, 0x7f7f7f7f, 0, 0x7f7f7f7f);
}

// Fused dual-GEMM (MX-fp8 16x16x128) + KL partial sums — m201-style 4-phase
// interleave. BM=256 x BN=128, 8 waves (4wr x 2wc of 64x64 dual), grid 256
// (1 block/CU). A from L2 (fragment-linear). W in LDS, 4-deep buffers
// (4 x 32KB = 128KB): stage(t+2) spread 1 gload_lds/phase; step-entry gate
// waits vmcnt(12) = {stage(t+1) x4 + As(t) x8} outstanding -> stage(t) and all
// older retired (FIFO), never a hot drain. Phases: p0/p1 = student ni{0,1}/
// {2,3}, p2/p3 = teacher; each = {4 B ds_reads; 1 stage; [A-issue]; s_barrier;
// lgkmcnt(0)+sched_barrier; setprio(1); 8 MFMA; setprio(0)}. B ds_read stream
// = r9's (HW-verified 0 bank conflicts).
__global__ __launch_bounds__(512, 2) void fused_kl(
    const unsigned char* __restrict__ xF, const unsigned char* __restrict__ txF,
    const unsigned char* __restrict__ ws8, const unsigned char* __restrict__ wt8,
    float* __restrict__ Zt, float* __restrict__ Uu, float* __restrict__ Zs) {
  __shared__ __align__(16) char smem[131072];  // buf k @ k*32KB: Ws@+0, Wt@+16KB

  const unsigned tid = threadIdx.x;
  const unsigned lane = tid & 63u;
  const unsigned w = tid >> 6;           // wave 0..7
  const unsigned wr = w >> 1, wc = w & 1u;

  const unsigned b = blockIdx.x;
  const unsigned rb = (b & 7u) * 2u + ((b >> 3) & 1u);  // row-block 0..15 (256 rows)
  const unsigned chunk = b >> 4;                        // vocab chunk 0..15
  const unsigned row0 = rb * 256u;
  const unsigned t_begin = chunk * 15u + (chunk < 10u ? chunk : 10u);
  const unsigned t_count = (chunk < 10u) ? 16u : 15u;
  const unsigned NK = t_count * 8u;

  const unsigned c = lane & 15u;
  const unsigned g = (lane >> 4) & 3u;
  const unsigned key = (c & 7u) << 4;

  // B ds_read byte offsets within one 16KB W tile (r9-verified 0-conflict).
  const unsigned f0 = (g << 4) ^ key;
  const unsigned f1 = (64u | (g << 4)) ^ key;
  const unsigned bB0 = (wc * 64u + c) * 128u + f0;
  const unsigned bB1 = (wc * 64u + c) * 128u + f1;

  // A fragment-linear base: row-group rg0 = rb*16 + wr*4.
  const unsigned aoff0 = (rb * 16u + wr * 4u) * 16384u + lane * 16u;

  // W staging: waves 0-3 stage Ws rows (w&3)*32..+32, waves 4-7 Wt.
  const unsigned char* gW = (w < 4u) ? ws8 : wt8;
  const unsigned wtoff = (w >= 4u) ? 16384u : 0u;
  const unsigned wrow0 = (w & 3u) * 32u;
  const unsigned srow = lane >> 3;
  const unsigned sb = (lane & 7u) * 16u;
  char* sd_base = smem + wtoff + (w & 3u) * 4096u + lane * 16u;

  auto stage_one = [&](unsigned step, unsigned i) {
    if (step < NK) {
      unsigned vtp = step >> 3, ktp = step & 7u;
      char* dst = sd_base + (step & 3u) * 32768u + i * 1024u;
      const unsigned char* s0 = gW +
          (size_t)((t_begin + vtp) * 128u + wrow0 + i * 8u + srow) * H_DIM + ktp * 128u + sb;
      __builtin_amdgcn_global_load_lds((gas_ptr)s0, (las_ptr)dst, 16, 0, 0);
    }
  };

  i32x4 as0[4], as1[4], at0[4], at1[4];
  auto loadA = [&](const unsigned char* base, unsigned ktp, i32x4* a0, i32x4* a1) {
#pragma unroll
    for (int mi = 0; mi < 4; ++mi) {
      const unsigned char* pa = base + aoff0 + (unsigned)mi * 16384u + ktp * 2048u;
      a0[mi] = *(const i32x4*)pa;
      a1[mi] = *(const i32x4*)(pa + 1024);
    }
  };

  float zt1 = 0.f, uu1 = 0.f, zs1 = 0.f;
  const f32x4 fzero = {0.f, 0.f, 0.f, 0.f};
  f32x4 acc_s[4][4], acc_t[4][4];

  // Prologue: stage(0), stage(1), As(0). Gate's vmcnt(12) drains stage(0).
#pragma unroll
  for (unsigned i = 0; i < 4; ++i) stage_one(0, i);
#pragma unroll
  for (unsigned i = 0; i < 4; ++i) stage_one(1, i);
  loadA(xF, 0, as0, as1);

  for (unsigned t = 0; t < NK; ++t) {
    const unsigned kt = t & 7u;
    const unsigned bufo = (t & 3u) * 32768u;

    // ---- step gate: counted wait, then block barrier ----
    asm volatile("s_waitcnt vmcnt(12)" ::: "memory");
    __builtin_amdgcn_sched_barrier(0);
    __builtin_amdgcn_s_barrier();
    __builtin_amdgcn_sched_barrier(0);

    if (kt == 0u) {
#pragma unroll
      for (int mi = 0; mi < 4; ++mi)
#pragma unroll
        for (int ni = 0; ni < 4; ++ni) { acc_s[mi][ni] = fzero; acc_t[mi][ni] = fzero; }
    }

    // ================= phase 0: student ni 0,1 =================
    {
      const char* q = smem + bufo;
      i32x4 b0a = *(const i32x4*)(q + bB0);
      i32x4 b0b = *(const i32x4*)(q + bB1);
      i32x4 b1a = *(const i32x4*)(q + 2048 + bB0);
      i32x4 b1b = *(const i32x4*)(q + 2048 + bB1);
      stage_one(t + 2u, 0);
      __builtin_amdgcn_s_barrier();
      asm volatile("s_waitcnt lgkmcnt(0)" ::: "memory");
      __builtin_amdgcn_sched_barrier(0);
      __builtin_amdgcn_s_setprio(1);
#pragma unroll
      for (int mi = 0; mi < 4; ++mi)
        acc_s[mi][0] = mx_mfma(cat8(as0[mi], as1[mi]), cat8(b0a, b0b), acc_s[mi][0]);
#pragma unroll
      for (int mi = 0; mi < 4; ++mi)
        acc_s[mi][1] = mx_mfma(cat8(as0[mi], as1[mi]), cat8(b1a, b1b), acc_s[mi][1]);
      __builtin_amdgcn_s_setprio(0);
    }
    // ================= phase 1: student ni 2,3 (+ issue At) =================
    {
      const char* q = smem + bufo + 4096u;
      i32x4 b0a = *(const i32x4*)(q + bB0);
      i32x4 b0b = *(const i32x4*)(q + bB1);
      i32x4 b1a = *(const i32x4*)(q + 2048 + bB0);
      i32x4 b1b = *(const i32x4*)(q + 2048 + bB1);
      stage_one(t + 2u, 1);
      loadA(txF, kt, at0, at1);  // used in p2 -> one-phase latency cover
      __builtin_amdgcn_s_barrier();
      asm volatile("s_waitcnt lgkmcnt(0)" ::: "memory");
      __builtin_amdgcn_sched_barrier(0);
      __builtin_amdgcn_s_setprio(1);
#pragma unroll
      for (int mi = 0; mi < 4; ++mi)
        acc_s[mi][2] = mx_mfma(cat8(as0[mi], as1[mi]), cat8(b0a, b0b), acc_s[mi][2]);
#pragma unroll
      for (int mi = 0; mi < 4; ++mi)
        acc_s[mi][3] = mx_mfma(cat8(as0[mi], as1[mi]), cat8(b1a, b1b), acc_s[mi][3]);
      __builtin_amdgcn_s_setprio(0);
    }
    // ================= phase 2: teacher ni 0,1 =================
    {
      const char* q = smem + bufo + 16384u;
      i32x4 b0a = *(const i32x4*)(q + bB0);
      i32x4 b0b = *(const i32x4*)(q + bB1);
      i32x4 b1a = *(const i32x4*)(q + 2048 + bB0);
      i32x4 b1b = *(const i32x4*)(q + 2048 + bB1);
      stage_one(t + 2u, 2);
      __builtin_amdgcn_s_barrier();
      asm volatile("s_waitcnt lgkmcnt(0)" ::: "memory");
      __builtin_amdgcn_sched_barrier(0);
      __builtin_amdgcn_s_setprio(1);
#pragma unroll
      for (int mi = 0; mi < 4; ++mi)
        acc_t[mi][0] = mx_mfma(cat8(at0[mi], at1[mi]), cat8(b0a, b0b), acc_t[mi][0]);
#pragma unroll
      for (int mi = 0; mi < 4; ++mi)
        acc_t[mi][1] = mx_mfma(cat8(at0[mi], at1[mi]), cat8(b1a, b1b), acc_t[mi][1]);
      __builtin_amdgcn_s_setprio(0);
    }
    // ================= phase 3: teacher ni 2,3 (+ issue As(t+1)) =================
    {
      const char* q = smem + bufo + 16384u + 4096u;
      i32x4 b0a = *(const i32x4*)(q + bB0);
      i32x4 b0b = *(const i32x4*)(q + bB1);
      i32x4 b1a = *(const i32x4*)(q + 2048 + bB0);
      i32x4 b1b = *(const i32x4*)(q + 2048 + bB1);
      if (t + 1u < NK) loadA(xF, (t + 1u) & 7u, as0, as1);  // as dead since p1
      stage_one(t + 2u, 3);
      __builtin_amdgcn_s_barrier();
      asm volatile("s_waitcnt lgkmcnt(0)" ::: "memory");
      __builtin_amdgcn_sched_barrier(0);
      __builtin_amdgcn_s_setprio(1);
#pragma unroll
      for (int mi = 0; mi < 4; ++mi)
        acc_t[mi][2] = mx_mfma(cat8(at0[mi], at1[mi]), cat8(b0a, b0b), acc_t[mi][2]);
#pragma unroll
      for (int mi = 0; mi < 4; ++mi)
        acc_t[mi][3] = mx_mfma(cat8(at0[mi], at1[mi]), cat8(b1a, b1b), acc_t[mi][3]);
      __builtin_amdgcn_s_setprio(0);
    }

    // ---- per-vocab-tile epilogue (registers + shfl only) ----
    if (kt == 7u) {
      // C/D layout: col = lane&15, row = (lane>>4)*4 + j (m89-verified)
#pragma unroll
      for (int mi = 0; mi < 4; ++mi)
#pragma unroll
        for (int j = 0; j < 4; ++j) {
          float ztl = 0.f, uul = 0.f, zsl = 0.f;
#pragma unroll
          for (int ni = 0; ni < 4; ++ni) {
            float s = acc_s[mi][ni][j];
            float tt = acc_t[mi][ni][j];
            float et = __expf(tt);
            ztl += et;
            uul += et * (tt - s);
            zsl += __expf(s);
          }
          ztl += __shfl_xor(ztl, 1); ztl += __shfl_xor(ztl, 2);
          ztl += __shfl_xor(ztl, 4); ztl += __shfl_xor(ztl, 8);
          uul += __shfl_xor(uul, 1); uul += __shfl_xor(uul, 2);
          uul += __shfl_xor(uul, 4); uul += __shfl_xor(uul, 8);
          zsl += __shfl_xor(zsl, 1); zsl += __shfl_xor(zsl, 2);
          zsl += __shfl_xor(zsl, 4); zsl += __shfl_xor(zsl, 8);
          if (c == (unsigned)(mi * 4 + j)) { zt1 += ztl; uu1 += uul; zs1 += zsl; }
        }
    }
  }

  // Lane (g,c) owns row: wr*64 + (c>>2)*16 + g*4 + (c&3)  (bijective over 64 rows)
  {
    unsigned n = row0 + wr * 64u + (c >> 2) * 16u + g * 4u + (c & 3u);
    atomicAdd(&Zt[n], zt1);
    atomicAdd(&Uu[n], uu1);
    atomicAdd(&Zs[n], zs1);
  }
}

// KL_n = U/Zt - log Zt + log Zs ; out = mean over N, float32.
__global__ void finalize_kl(const float* __restrict__ Zt, const float* __restrict__ Uu,
                            const float* __restrict__ Zs, float* __restrict__ out) {
  __shared__ float red[4];
  float s = 0.f;
  for (int r = threadIdx.x; r < N_ROWS; r += 256) {
    s += Uu[r] / Zt[r] - __logf(Zt[r]) + __logf(Zs[r]);
  }
  s += __shfl_xor(s, 1); s += __shfl_xor(s, 2); s += __shfl_xor(s, 4);
  s += __shfl_xor(s, 8); s += __shfl_xor(s, 16); s += __shfl_xor(s, 32);
  if ((threadIdx.x & 63) == 0) red[threadIdx.x >> 6] = s;
  __syncthreads();
  if (threadIdx.x == 0) {
    float tot = red[0] + red[1] + red[2] + red[3];
    out[0] = tot / (float)N_ROWS;
  }
}

extern "C" void kernel_launch(void* const* d_in, const int* in_sizes, int n_in,
                              void* d_out, int out_size, void* d_ws, size_t ws_size,
                              hipStream_t stream) {
  const float* x  = (const float*)d_in[0];
  const float* tx = (const float*)d_in[1];
  const float* Ws = (const float*)d_in[2];
  const float* Wt = (const float*)d_in[3];

  char* ws = (char*)d_ws;
  float* Zt = (float*)ws;
  float* Uu = Zt + N_ROWS;
  float* Zs = Uu + N_ROWS;
  unsigned char* xF  = (unsigned char*)(ws + 65536);
  unsigned char* txF = xF  + (size_t)N_ROWS * H_DIM;
  unsigned char* ws8 = txF + (size_t)N_ROWS * H_DIM;
  unsigned char* wt8 = ws8 + (size_t)V_SIZE * H_DIM;

  zero_f32<<<(3 * N_ROWS) / 256, 256, 0, stream>>>(Zt, 3 * N_ROWS);
  cvt_fragA<<<1024, 256, 0, stream>>>(x,  xF,  N_ROWS * (H_DIM / 16));
  cvt_fragA<<<1024, 256, 0, stream>>>(tx, txF, N_ROWS * (H_DIM / 16));
  cvt_fp8<<<2048, 256, 0, stream>>>(Ws, ws8, V_SIZE * (H_DIM / 16));
  cvt_fp8<<<2048, 256, 0, stream>>>(Wt, wt8, V_SIZE * (H_DIM / 16));
  fused_kl<<<256, 512, 0, stream>>>(xF, txF, ws8, wt8, Zt, Uu, Zs);
  finalize_kl<<<1, 256, 0, stream>>>(Zt, Uu, Zs, (float*)d_out);
}

// Round 15
// 498.493 us; speedup vs baseline: 3.6007x; 3.6007x over previous
//
#include <hip/hip_runtime.h>
#include <hip/hip_fp8.h>

#define N_ROWS 4096
#define H_DIM  1024
#define V_SIZE 32000

typedef int   i32x4 __attribute__((ext_vector_type(4)));
typedef int   i32x8 __attribute__((ext_vector_type(8)));
typedef float f32x4 __attribute__((ext_vector_type(4)));

typedef __attribute__((address_space(1))) void* gas_ptr;
typedef __attribute__((address_space(3))) void* las_ptr;

__global__ void zero_f32(float* __restrict__ p, int n) {
  int i = blockIdx.x * blockDim.x + threadIdx.x;
  if (i < n) p[i] = 0.0f;
}

__device__ __forceinline__ unsigned pk4_fp8(float a, float b, float c, float d) {
#if __has_builtin(__builtin_amdgcn_cvt_pk_fp8_f32)
  int v = __builtin_amdgcn_cvt_pk_fp8_f32(a, b, 0, false);
  v = __builtin_amdgcn_cvt_pk_fp8_f32(c, d, v, true);
  return (unsigned)v;
#else
  __hip_fp8_e4m3 qa(a), qb(b), qc(c), qd(d);
  return (unsigned)qa.__x | ((unsigned)qb.__x << 8) | ((unsigned)qc.__x << 16) |
         ((unsigned)qd.__x << 24);
#endif
}

// fp32 -> fp8 e4m3 with the LDS swizzle PRE-BAKED into the HBM layout
// (r9-verified 0-conflict): out[row*1024 + (k ^ ((row&7)<<4))] = fp8(in[row][k]).
__global__ void cvt_fp8(const float* __restrict__ in, unsigned char* __restrict__ out, int total16) {
  int idx = blockIdx.x * blockDim.x + threadIdx.x;
  int stride = gridDim.x * blockDim.x;
  for (; idx < total16; idx += stride) {
    unsigned row = (unsigned)idx >> 6;
    unsigned k0 = ((unsigned)idx & 63u) << 4;
    const float4* p = (const float4*)(in + (size_t)row * H_DIM + k0);
    float4 f0 = p[0], f1 = p[1], f2 = p[2], f3 = p[3];
    unsigned long long u0 = (unsigned long long)pk4_fp8(f0.x, f0.y, f0.z, f0.w) |
                            ((unsigned long long)pk4_fp8(f1.x, f1.y, f1.z, f1.w) << 32);
    unsigned long long u1 = (unsigned long long)pk4_fp8(f2.x, f2.y, f2.z, f2.w) |
                            ((unsigned long long)pk4_fp8(f3.x, f3.y, f3.z, f3.w) << 32);
    unsigned key = (row & 7u) << 4;
    unsigned char* ob = out + (size_t)row * H_DIM;
    *(unsigned long long*)(ob + (k0 ^ key)) = u0;
    *(unsigned long long*)(ob + ((k0 ^ key) + 8u)) = u1;
  }
}

__device__ __forceinline__ i32x8 cat8(i32x4 a, i32x4 b) {
  return __builtin_shufflevector(a, b, 0, 1, 2, 3, 4, 5, 6, 7);
}

// MX-scaled fp8 MFMA, unit scales (E8M0 127 = x1.0). Validated r8/r9.
__device__ __forceinline__ f32x4 mx_mfma(i32x8 a, i32x8 b, f32x4 c) {
  return __builtin_amdgcn_mfma_scale_f32_16x16x128_f8f6f4(
      a, b, c, 0 /*A=fp8*/, 0 /*B=fp8*/, 0, 0x7f7f7f7f, 0, 0x7f7f7f7f);
}

#define RED4(v) do { v += __shfl_xor(v,1); v += __shfl_xor(v,2); \
                     v += __shfl_xor(v,4); v += __shfl_xor(v,8); } while(0)

// Fused dual-GEMM (MX-fp8 16x16x128) + KL, SPLIT-GEMM waves:
// waves 0-3 = student (x*Ws), waves 4-7 = teacher (tx*Wt); each wave owns a
// 64x64 tile of ONE gemm -> acc = 64 VGPRs -> launch_bounds(512,4) fits 128
// VGPR -> 2 blocks/CU x 8 waves = 16 waves/CU (4/SIMD) — 2x the occupancy of
// every previous round (the r9..r13 plateau's binding constraint).
// KL coupling: U = sum exp(t)*t  -  sum exp(t)*s. First term teacher-local;
// for the second, at each vocab-tile boundary teacher waves write exp(t)
// into the (dead) tile region of LDS (stride-4 f32 = 2-way, free), student
// waves read it and accumulate -exp(t)*s into Uu. Zt teacher-local, Zs
// student-local. Loop structure, 0-conflict ds streams, staging = r9's.
__global__ __launch_bounds__(512, 4) void fused_kl(
    const unsigned char* __restrict__ xq, const unsigned char* __restrict__ txq,
    const unsigned char* __restrict__ wsq, const unsigned char* __restrict__ wtq,
    float* __restrict__ Zt, float* __restrict__ Uu, float* __restrict__ Zs) {
  __shared__ __align__(16) char smem[65536];  // x@0 | tx@16K | Ws@32K | Wt@48K

  const unsigned tid = threadIdx.x;
  const unsigned lane = tid & 63u;
  const unsigned w = tid >> 6;            // 0..7
  const bool teach = (w >= 4u);
  const unsigned widx = w & 3u;           // tile index within gemm
  const unsigned wr = widx >> 1, wc = widx & 1u;

  const unsigned b = blockIdx.x;
  const unsigned rb = (b & 7u) * 4u + ((b >> 3) & 3u);  // row-block 0..31
  const unsigned chunk = b >> 5;                        // vocab chunk 0..15
  const unsigned row0 = rb * 128u;
  const unsigned t_begin = chunk * 15u + (chunk < 10u ? chunk : 10u);
  const unsigned t_count = (chunk < 10u) ? 16u : 15u;

  const unsigned c = lane & 15u;
  const unsigned g = (lane >> 4) & 3u;
  const unsigned key = (c & 7u) << 4;
  const unsigned f0 = (g << 4) ^ key;
  const unsigned f1 = (64u | (g << 4)) ^ key;
  const unsigned tsel = teach ? 16384u : 0u;

  // ds_read bases (r9-identical 0-conflict stream; mi/ni via +2048 imms)
  const char* pA0 = smem + tsel + (wr * 64u + c) * 128u + f0;
  const char* pA1 = smem + tsel + (wr * 64u + c) * 128u + f1;
  const char* pB0 = smem + 32768u + tsel + (wc * 64u + c) * 128u + f0;
  const char* pB1 = smem + 32768u + tsel + (wc * 64u + c) * 128u + f1;

  // Staging: wave w fills 8KB region (w>>1)*16K + (w&1)*8K (half a tile).
  const unsigned char* gsrc = (w < 2u) ? xq : (w < 4u) ? txq : (w < 6u) ? wsq : wtq;
  const bool aTile = (w < 4u);
  char* sdst = smem + (w >> 1) * 16384u + (w & 1u) * 8192u + lane * 16u;
  const unsigned srow = (w & 1u) * 64u + (lane >> 3);
  const unsigned sb = (lane & 7u) * 16u;

  float zt1 = 0.f, uu1 = 0.f, zs1 = 0.f;
  const f32x4 fzero = {0.f, 0.f, 0.f, 0.f};
  f32x4 acc[4][4];

  float* exch = (float*)smem;                 // vt-boundary exchange (dead tiles)
  const unsigned exb = widx * 4096u + lane;   // float index; elem e at +e*64

  for (unsigned vt = 0; vt < t_count; ++vt) {
    const unsigned trow = aTile ? row0 : (t_begin + vt) * 128u;
    const unsigned char* sv = gsrc + (size_t)(trow + srow) * H_DIM + sb;

#pragma unroll
    for (int mi = 0; mi < 4; ++mi)
#pragma unroll
      for (int ni = 0; ni < 4; ++ni) acc[mi][ni] = fzero;

    for (unsigned kt = 0; kt < 8; ++kt) {
      __syncthreads();  // prev reads (or exchange) done before overwrite
      {
        const unsigned char* s0 = sv + kt * 128u;
#pragma unroll
        for (unsigned i = 0; i < 8; ++i)
          __builtin_amdgcn_global_load_lds((gas_ptr)(s0 + (size_t)i * (8u * H_DIM)),
                                           (las_ptr)(sdst + i * 1024u), 16, 0, 0);
      }
      __syncthreads();  // staging visible

      i32x8 B0 = cat8(*(const i32x4*)(pB0), *(const i32x4*)(pB1));
      i32x8 B1 = cat8(*(const i32x4*)(pB0 + 2048), *(const i32x4*)(pB1 + 2048));
      i32x8 B2 = cat8(*(const i32x4*)(pB0 + 4096), *(const i32x4*)(pB1 + 4096));
      i32x8 B3 = cat8(*(const i32x4*)(pB0 + 6144), *(const i32x4*)(pB1 + 6144));
      __builtin_amdgcn_s_setprio(1);
#pragma unroll
      for (int mi = 0; mi < 4; ++mi) {
        i32x8 A = cat8(*(const i32x4*)(pA0 + mi * 2048), *(const i32x4*)(pA1 + mi * 2048));
        acc[mi][0] = mx_mfma(A, B0, acc[mi][0]);
        acc[mi][1] = mx_mfma(A, B1, acc[mi][1]);
        acc[mi][2] = mx_mfma(A, B2, acc[mi][2]);
        acc[mi][3] = mx_mfma(A, B3, acc[mi][3]);
      }
      __builtin_amdgcn_s_setprio(0);
    }

    // ---- vocab-tile boundary: KL fold + cross-term exchange ----
    __syncthreads();  // all tile reads done; region reusable
    if (teach) {
      // write exp(t); accumulate Zt and +sum exp(t)*t locally
#pragma unroll
      for (int mi = 0; mi < 4; ++mi)
#pragma unroll
        for (int j = 0; j < 4; ++j) {
          float ztl = 0.f, t1l = 0.f;
#pragma unroll
          for (int ni = 0; ni < 4; ++ni) {
            float tt = acc[mi][ni][j];
            float et = __expf(tt);
            exch[exb + (unsigned)(mi * 16 + ni * 4 + j) * 64u] = et;
            ztl += et;
            t1l += et * tt;
          }
          RED4(ztl); RED4(t1l);
          if (c == (unsigned)(mi * 4 + j)) { zt1 += ztl; uu1 += t1l; }
        }
    } else {
      // student-local Zs while teacher writes
#pragma unroll
      for (int mi = 0; mi < 4; ++mi)
#pragma unroll
        for (int j = 0; j < 4; ++j) {
          float zsl = 0.f;
#pragma unroll
          for (int ni = 0; ni < 4; ++ni) zsl += __expf(acc[mi][ni][j]);
          RED4(zsl);
          if (c == (unsigned)(mi * 4 + j)) zs1 += zsl;
        }
    }
    __syncthreads();  // exp(t) visible
    if (!teach) {
      // cross term: -sum exp(t)*s (exchange is lane-identical mapping)
#pragma unroll
      for (int mi = 0; mi < 4; ++mi)
#pragma unroll
        for (int j = 0; j < 4; ++j) {
          float s1l = 0.f;
#pragma unroll
          for (int ni = 0; ni < 4; ++ni)
            s1l += exch[exb + (unsigned)(mi * 16 + ni * 4 + j) * 64u] * acc[mi][ni][j];
          RED4(s1l);
          if (c == (unsigned)(mi * 4 + j)) uu1 -= s1l;
        }
    }
    // next vt's kt=0 staging is fenced by the kt-loop-top __syncthreads
  }

  // Lane (g,c) owns row: wr*64 + (c>>2)*16 + g*4 + (c&3)  (bijective over 64)
  {
    unsigned n = row0 + wr * 64u + (c >> 2) * 16u + g * 4u + (c & 3u);
    if (teach) {
      atomicAdd(&Zt[n], zt1);
      atomicAdd(&Uu[n], uu1);   // +sum exp(t)*t
    } else {
      atomicAdd(&Zs[n], zs1);
      atomicAdd(&Uu[n], uu1);   // -sum exp(t)*s
    }
  }
}

// KL_n = Uu/Zt - log Zt + log Zs ; out = mean over N, float32.
__global__ void finalize_kl(const float* __restrict__ Zt, const float* __restrict__ Uu,
                            const float* __restrict__ Zs, float* __restrict__ out) {
  __shared__ float red[4];
  float s = 0.f;
  for (int r = threadIdx.x; r < N_ROWS; r += 256) {
    s += Uu[r] / Zt[r] - __logf(Zt[r]) + __logf(Zs[r]);
  }
  s += __shfl_xor(s, 1); s += __shfl_xor(s, 2); s += __shfl_xor(s, 4);
  s += __shfl_xor(s, 8); s += __shfl_xor(s, 16); s += __shfl_xor(s, 32);
  if ((threadIdx.x & 63) == 0) red[threadIdx.x >> 6] = s;
  __syncthreads();
  if (threadIdx.x == 0) {
    float tot = red[0] + red[1] + red[2] + red[3];
    out[0] = tot / (float)N_ROWS;
  }
}

extern "C" void kernel_launch(void* const* d_in, const int* in_sizes, int n_in,
                              void* d_out, int out_size, void* d_ws, size_t ws_size,
                              hipStream_t stream) {
  const float* x  = (const float*)d_in[0];
  const float* tx = (const float*)d_in[1];
  const float* Ws = (const float*)d_in[2];
  const float* Wt = (const float*)d_in[3];

  char* ws = (char*)d_ws;
  float* Zt = (float*)ws;
  float* Uu = Zt + N_ROWS;
  float* Zs = Uu + N_ROWS;
  unsigned char* xq  = (unsigned char*)(ws + 65536);
  unsigned char* txq = xq  + (size_t)N_ROWS * H_DIM;
  unsigned char* wsq = txq + (size_t)N_ROWS * H_DIM;
  unsigned char* wtq = wsq + (size_t)V_SIZE * H_DIM;

  zero_f32<<<(3 * N_ROWS) / 256, 256, 0, stream>>>(Zt, 3 * N_ROWS);
  cvt_fp8<<<1024, 256, 0, stream>>>(x,  xq,  N_ROWS * (H_DIM / 16));
  cvt_fp8<<<1024, 256, 0, stream>>>(tx, txq, N_ROWS * (H_DIM / 16));
  cvt_fp8<<<2048, 256, 0, stream>>>(Ws, wsq, V_SIZE * (H_DIM / 16));
  cvt_fp8<<<2048, 256, 0, stream>>>(Wt, wtq, V_SIZE * (H_DIM / 16));
  fused_kl<<<512, 512, 0, stream>>>(xq, txq, wsq, wtq, Zt, Uu, Zs);
  finalize_kl<<<1, 256, 0, stream>>>(Zt, Uu, Zs, (float*)d_out);
}